// Round 10
// baseline (230.068 us; speedup 1.0000x reference)
//
#include <hip/hip_runtime.h>
#include <hip/hip_bf16.h>
#include <math.h>

#define NB 2
#define NT 256
#define NN 512
#define NH 64
#define NS 8
#define NC 8

// workspace layout (float offsets)
#define OFF_H      0                    // 2*512*64 = 65536
#define OFF_PVEC   65536                // 65536   (pre_i + be1)
#define OFF_INVN   131072               // 1024
#define OFF_WA     132096               // 4096 shorts = 2048 floats
#define OFF_WJF    134144               // 4096 floats
#define OFF_WPF    138240               // 4096 floats
#define OFF_UNSYM  142336               // 524288
#define OFF_LOGIT  (142336 + 524288)    // 524288

typedef __attribute__((ext_vector_type(8))) short short8;
typedef __attribute__((ext_vector_type(4))) float f32x4;
typedef __attribute__((ext_vector_type(4))) unsigned uint4v;

__device__ __forceinline__ float softplusf(float x){
  if (x > 20.f) return x;
  return log1pf(expf(x));
}

__device__ __forceinline__ short f2bf(float x){
  __hip_bfloat16 h = __float2bfloat16(x);
  return __builtin_bit_cast(short, h);
}

__device__ __forceinline__ unsigned cvtpk(float a, float b){
  unsigned r;
  asm("v_cvt_pk_bf16_f32 %0, %1, %2" : "=v"(r) : "v"(a), "v"(b));
  return r;
}

__device__ __forceinline__ void keep8(short8 &v){
  asm volatile("" : "+v"(v));
}
__device__ __forceinline__ void keepf(float v){
  asm volatile("" :: "v"(v));
}

template<int CTRL>
__device__ __forceinline__ float dpp_addf(float x){
  int xi = __builtin_bit_cast(int, x);
  int yi = __builtin_amdgcn_update_dpp(0, xi, CTRL, 0xF, 0xF, true);
  return x + __builtin_bit_cast(float, yi);
}
__device__ __forceinline__ float row16_sum(float x){
  x = dpp_addf<0xB1>(x);
  x = dpp_addf<0x4E>(x);
  x = dpp_addf<0x141>(x);
  x = dpp_addf<0x140>(x);
  return x;
}

// ---------------- Kernel FRONT (unchanged) ----------------
__global__ __launch_bounds__(256) void k_front(
    const float* __restrict__ x, const float* __restrict__ mask,
    const float* __restrict__ sctx,
    const float* __restrict__ W1, const float* __restrict__ b1,
    const float* __restrict__ W2, const float* __restrict__ b2,
    const float* __restrict__ We1, const float* __restrict__ be1,
    float* __restrict__ hg, float* __restrict__ pvec,
    float* __restrict__ invn, short* __restrict__ wa_bf,
    float* __restrict__ wjf, float* __restrict__ wpf){
  int blk = blockIdx.x;
  int tid = threadIdx.x;

  if (blk >= 256){
    int pidx = (blk - 256)*256 + tid;
    int e    = pidx & 7;
    int lane = (pidx >> 3) & 63;
    int frag = (pidx >> 9) & 7;
    int nt = frag & 3, ks = frag >> 2;
    int kg = lane >> 4, q = lane & 15;
    int kk = ks*32 + kg*8 + e;
    int c  = nt*16 + q;
    if (pidx < 4096){
      wa_bf[pidx] = f2bf(We1[(128 + kk)*NH + c]);
    } else if (pidx < 8192){
      wjf[pidx - 4096] = We1[(64 + kk)*NH + c];
    } else {
      wpf[pidx - 8192] = We1[(192 + kk)*NH + c];
    }
    return;
  }

  int b  = blk >> 7;
  int n0 = (blk & 127) * 4;

  int nl = tid & 3;
  int ts = tid >> 2;
  int n  = n0 + nl;

  float cnt = 0.f, sx = 0.f, sxx = 0.f;
  int lastt = 0;
  for (int t = ts*4; t < ts*4 + 4; ++t){
    int idx = (b*NT + t)*NN + n;
    float xv = x[idx];
    float mv = mask[idx];
    bool obs = (mv < 0.5f);
    if (obs){ cnt += 1.f; sx += xv; sxx += xv*xv; lastt = t; }
  }
  #pragma unroll
  for (int m = 4; m < 64; m <<= 1){
    cnt   += __shfl_xor(cnt,  m);
    sx    += __shfl_xor(sx,   m);
    sxx   += __shfl_xor(sxx,  m);
    lastt  = max(lastt, __shfl_xor(lastt, m));
  }
  int w = tid >> 6;
  __shared__ float r_cnt[4][4], r_sx[4][4], r_sxx[4][4];
  __shared__ int   r_lt[4][4];
  __shared__ float s_dyn[4][4];
  if ((tid & 63) < 4){
    r_cnt[w][nl] = cnt; r_sx[w][nl] = sx; r_sxx[w][nl] = sxx; r_lt[w][nl] = lastt;
  }
  __syncthreads();
  if (tid < 4){
    float c = 0.f, s1 = 0.f, s2 = 0.f; int lt = 0;
    #pragma unroll
    for (int ww = 0; ww < 4; ++ww){
      c  += r_cnt[ww][tid]; s1 += r_sx[ww][tid]; s2 += r_sxx[ww][tid];
      lt  = max(lt, r_lt[ww][tid]);
    }
    float cc   = fmaxf(c, 1.f);
    float mean = s1 / cc;
    float var  = s2 / cc - mean*mean;
    float stdv = sqrtf(fmaxf(var, 0.f) + 1e-6f);
    float last = x[(b*NT + lt)*NN + n0 + tid];
    float mr   = 1.f - c * (1.f/(float)NT);
    s_dyn[tid][0] = mean; s_dyn[tid][1] = stdv; s_dyn[tid][2] = last; s_dyn[tid][3] = mr;
  }
  __syncthreads();

  int c = tid & 63;
  int gn = n0 + w;
  int bn = b*NN + gn;
  __shared__ float s_f[4][12];
  __shared__ float s_h1[4][64];
  __shared__ float s_h2[4][64];

  if (c < 4)       s_f[w][c] = s_dyn[w][c];
  else if (c < 12) s_f[w][c] = sctx[gn*NS + (c-4)];
  __syncthreads();

  float a = b1[c];
  #pragma unroll
  for (int k = 0; k < 12; ++k) a = fmaf(s_f[w][k], W1[k*NH + c], a);
  s_h1[w][c] = fmaxf(a, 0.f);
  __syncthreads();

  float a2 = b2[c];
  #pragma unroll 8
  for (int k = 0; k < 64; ++k) a2 = fmaf(s_h1[w][k], W2[k*NH + c], a2);
  a2 = fmaxf(a2, 0.f);

  float sq = a2*a2;
  #pragma unroll
  for (int m = 1; m < 64; m <<= 1) sq += __shfl_xor(sq, m);
  float inv = 1.f / fmaxf(sqrtf(sq), 1e-12f);

  s_h2[w][c] = a2;
  __syncthreads();

  float pi = be1[c];
  #pragma unroll 8
  for (int k = 0; k < 64; ++k) pi = fmaf(s_h2[w][k], We1[k*NH + c], pi);

  hg  [bn*64 + c] = a2;
  pvec[bn*64 + c] = pi;
  if (c == 0) invn[bn] = inv;
}

// ================= shared ablation body =================
// flag bits: 1=LOAD hj, 2=FEAT, 4=MFMA, 8=EPI, 16=loop, 32=LDS-staged loads
template<int F>
__device__ __forceinline__ void abl_body(
    const float* __restrict__ hg, const float* __restrict__ pvec,
    const float* __restrict__ invn,
    const short* __restrict__ wa_bf, const float* __restrict__ wjf,
    const float* __restrict__ wpf, const float* __restrict__ coords,
    const float* __restrict__ We2, const float* __restrict__ be2,
    const float* __restrict__ s_sl, const float* __restrict__ s_ps,
    const float* __restrict__ s_ss,
    float* __restrict__ logits){
  constexpr bool DO_LOAD = (F & 1)  != 0;
  constexpr bool DO_FEAT = (F & 2)  != 0;
  constexpr bool DO_MFMA = (F & 4)  != 0;
  constexpr bool DO_EPI  = (F & 8)  != 0;
  constexpr bool DO_LOOP = (F & 16) != 0;
  constexpr bool DO_LDS  = (F & 32) != 0;

  int blk = blockIdx.x;
  int b = blk >> 9, i = blk & (NN-1);
  int tid  = threadIdx.x;
  int w    = tid >> 6;
  int lane = tid & 63;
  int q    = lane & 15;
  int kg   = lane >> 4;

  __shared__ __align__(16) float s_hi[64];
  __shared__ __align__(16) float s_pv[64];
  __shared__ __align__(16) float s_prior[NN];
  __shared__ __align__(16) float s_invn[NN];
  // per-wave private hj staging slices (only used when DO_LDS)
  __shared__ __align__(16) float s_hj[8][16*68 + 4];

  float spsl  = softplusf(s_sl[0]);
  float spps  = softplusf(s_ps[0]);
  float spss  = softplusf(s_ss[0]);

  if (tid < 64){
    s_hi[tid] = hg  [(b*NN + i)*64 + tid];
    s_pv[tid] = pvec[(b*NN + i)*64 + tid];
  }
  {
    float4 ci0 = *(const float4*)(coords + i*NC);
    float4 ci1 = *(const float4*)(coords + i*NC + 4);
    int j = tid;
    float4 cj0 = *(const float4*)(coords + j*NC);
    float4 cj1 = *(const float4*)(coords + j*NC + 4);
    float dd = 0.f;
    dd = fmaf(ci0.x-cj0.x, ci0.x-cj0.x, dd);
    dd = fmaf(ci0.y-cj0.y, ci0.y-cj0.y, dd);
    dd = fmaf(ci0.z-cj0.z, ci0.z-cj0.z, dd);
    dd = fmaf(ci0.w-cj0.w, ci0.w-cj0.w, dd);
    dd = fmaf(ci1.x-cj1.x, ci1.x-cj1.x, dd);
    dd = fmaf(ci1.y-cj1.y, ci1.y-cj1.y, dd);
    dd = fmaf(ci1.z-cj1.z, ci1.z-cj1.z, dd);
    dd = fmaf(ci1.w-cj1.w, ci1.w-cj1.w, dd);
    float dist = sqrtf(fmaxf(dd, 1e-12f));
    s_prior[j] = (j == i) ? 0.f : spps / (1.f + dist);
    s_invn[j]  = invn[b*NN + j];
  }
  __syncthreads();

  float hiA[16];
  {
    float4 t0 = *(const float4*)(s_hi + kg*8);
    float4 t1 = *(const float4*)(s_hi + kg*8 + 4);
    float4 t2 = *(const float4*)(s_hi + 32 + kg*8);
    float4 t3 = *(const float4*)(s_hi + 32 + kg*8 + 4);
    hiA[0]=t0.x; hiA[1]=t0.y; hiA[2]=t0.z; hiA[3]=t0.w;
    hiA[4]=t1.x; hiA[5]=t1.y; hiA[6]=t1.z; hiA[7]=t1.w;
    hiA[8]=t2.x; hiA[9]=t2.y; hiA[10]=t2.z; hiA[11]=t2.w;
    hiA[12]=t3.x; hiA[13]=t3.y; hiA[14]=t3.z; hiA[15]=t3.w;
  }

  short8 wa[2][4];
  #pragma unroll
  for (int ks = 0; ks < 2; ++ks)
    #pragma unroll
    for (int nt = 0; nt < 4; ++nt){
      wa[ks][nt] = *(const short8*)(wa_bf + ((ks*4 + nt)*64 + lane)*8);
      keep8(wa[ks][nt]);
    }

  short8 cw[2][4];
  #pragma unroll
  for (int ks2 = 0; ks2 < 2; ++ks2)
    #pragma unroll
    for (int nt = 0; nt < 4; ++nt){
      const float* wj = wjf + ((ks2*4 + nt)*64 + lane)*8;
      const float* wp = wpf + ((ks2*4 + nt)*64 + lane)*8;
      float4 j0 = *(const float4*)(wj);
      float4 j1 = *(const float4*)(wj + 4);
      float4 p0 = *(const float4*)(wp);
      float4 p1 = *(const float4*)(wp + 4);
      int hb = ks2*8;
      uint4v u;
      u[0] = cvtpk(fmaf(hiA[hb+0], p0.x, j0.x), fmaf(hiA[hb+1], p0.y, j0.y));
      u[1] = cvtpk(fmaf(hiA[hb+2], p0.z, j0.z), fmaf(hiA[hb+3], p0.w, j0.w));
      u[2] = cvtpk(fmaf(hiA[hb+4], p1.x, j1.x), fmaf(hiA[hb+5], p1.y, j1.y));
      u[3] = cvtpk(fmaf(hiA[hb+6], p1.z, j1.z), fmaf(hiA[hb+7], p1.w, j1.w));
      cw[ks2][nt] = __builtin_bit_cast(short8, u);
    }

  float pv4[4], we2q[4];
  #pragma unroll
  for (int nt = 0; nt < 4; ++nt){
    pv4[nt]  = s_pv[nt*16 + q];
    we2q[nt] = We2[nt*16 + q];
  }
  float invni = invn[b*NN + i];
  float be2v  = be2[0];
  int   srcl  = (lane & 48) | (((lane >> 4) & 3) << 2) | (lane & 3);
  float* lrowg = logits + (size_t)(b*NN + i) * NN;

  if constexpr (!DO_LOOP){
    #pragma unroll
    for (int ks = 0; ks < 2; ++ks)
      #pragma unroll
      for (int nt = 0; nt < 4; ++nt){ keep8(wa[ks][nt]); keep8(cw[ks][nt]); }
    keepf(pv4[0] + pv4[1] + pv4[2] + pv4[3]);
    keepf(we2q[0] + we2q[1] + we2q[2] + we2q[3]);
    keepf(hiA[0] + invni + be2v + spsl + (float)srcl);
    lrowg[tid] = hiA[0];
    return;
  }

  float* slice = &s_hj[w][0];

  #pragma unroll
  for (int s = 0; s < 4; ++s){
    int it = w + s*8;
    int jbase = it * 16;
    float hjA[16];
    if constexpr (DO_LDS){
      // coalesced stage: inst r loads rows r*4..r*4+3 fully (16 lines, no scatter)
      int rgrp = lane >> 4;       // 0..3
      int col4 = lane & 15;       // float4 index within 64-float row
      #pragma unroll
      for (int r = 0; r < 4; ++r){
        int row = r*4 + rgrp;
        float4 v = *(const float4*)(hg + (size_t)(b*NN + jbase + row)*64 + col4*4);
        *(float4*)(slice + row*68 + col4*4) = v;
      }
      // wave-private slice: same-wave ds ordering, no barrier needed
      float4 h0 = *(const float4*)(slice + q*68 + kg*8);
      float4 h1 = *(const float4*)(slice + q*68 + kg*8 + 4);
      float4 h2 = *(const float4*)(slice + q*68 + 32 + kg*8);
      float4 h3 = *(const float4*)(slice + q*68 + 32 + kg*8 + 4);
      hjA[0]=h0.x; hjA[1]=h0.y; hjA[2]=h0.z; hjA[3]=h0.w;
      hjA[4]=h1.x; hjA[5]=h1.y; hjA[6]=h1.z; hjA[7]=h1.w;
      hjA[8]=h2.x; hjA[9]=h2.y; hjA[10]=h2.z; hjA[11]=h2.w;
      hjA[12]=h3.x; hjA[13]=h3.y; hjA[14]=h3.z; hjA[15]=h3.w;
    } else if constexpr (DO_LOAD){
      const float* hjp = hg + (size_t)(b*NN + jbase + q)*64 + kg*8;
      float4 hj0 = *(const float4*)(hjp);
      float4 hj1 = *(const float4*)(hjp + 4);
      float4 hj2 = *(const float4*)(hjp + 32);
      float4 hj3 = *(const float4*)(hjp + 36);
      hjA[0]=hj0.x; hjA[1]=hj0.y; hjA[2]=hj0.z; hjA[3]=hj0.w;
      hjA[4]=hj1.x; hjA[5]=hj1.y; hjA[6]=hj1.z; hjA[7]=hj1.w;
      hjA[8]=hj2.x; hjA[9]=hj2.y; hjA[10]=hj2.z; hjA[11]=hj2.w;
      hjA[12]=hj3.x; hjA[13]=hj3.y; hjA[14]=hj3.z; hjA[15]=hj3.w;
    } else {
      float base = (float)(lane ^ (it << 2)) * 0.015625f;
      #pragma unroll
      for (int e = 0; e < 16; ++e) hjA[e] = base + (float)e * 0.0625f;
    }

    short8 af0, af1, af2, af3;
    float dotp;
    if constexpr (DO_FEAT){
      uint4v u0, u1, u2, u3;
      dotp = 0.f;
      #pragma unroll
      for (int w2 = 0; w2 < 4; ++w2){
        int e0 = 2*w2, e1 = 2*w2 + 1;
        u0[w2] = cvtpk(fabsf(hiA[e0]   - hjA[e0]),  fabsf(hiA[e1]   - hjA[e1]));
        u1[w2] = cvtpk(fabsf(hiA[8+e0] - hjA[8+e0]), fabsf(hiA[8+e1] - hjA[8+e1]));
        u2[w2] = cvtpk(hjA[e0],   hjA[e1]);
        u3[w2] = cvtpk(hjA[8+e0], hjA[8+e1]);
        dotp = fmaf(hiA[e0],   hjA[e0],   dotp);
        dotp = fmaf(hiA[e1],   hjA[e1],   dotp);
        dotp = fmaf(hiA[8+e0], hjA[8+e0], dotp);
        dotp = fmaf(hiA[8+e1], hjA[8+e1], dotp);
      }
      af0 = __builtin_bit_cast(short8, u0);
      af1 = __builtin_bit_cast(short8, u1);
      af2 = __builtin_bit_cast(short8, u2);
      af3 = __builtin_bit_cast(short8, u3);
    } else {
      #pragma unroll
      for (int e = 0; e < 16; ++e) keepf(hjA[e]);
      af0 = wa[0][0]; af1 = wa[0][1]; af2 = wa[1][2]; af3 = wa[1][3];
      dotp = hiA[0];
    }

    f32x4 acc[4];
    #pragma unroll
    for (int nt = 0; nt < 4; ++nt)
      acc[nt] = (f32x4){pv4[nt], pv4[nt], pv4[nt], pv4[nt]};
    if constexpr (DO_MFMA){
      #pragma unroll
      for (int nt = 0; nt < 4; ++nt){
        acc[nt] = __builtin_amdgcn_mfma_f32_16x16x32_bf16(af0, wa[0][nt], acc[nt], 0, 0, 0);
        acc[nt] = __builtin_amdgcn_mfma_f32_16x16x32_bf16(af1, wa[1][nt], acc[nt], 0, 0, 0);
        acc[nt] = __builtin_amdgcn_mfma_f32_16x16x32_bf16(af2, cw[0][nt], acc[nt], 0, 0, 0);
        acc[nt] = __builtin_amdgcn_mfma_f32_16x16x32_bf16(af3, cw[1][nt], acc[nt], 0, 0, 0);
      }
    } else {
      keep8(af0); keep8(af1); keep8(af2); keep8(af3);
    }

    if constexpr (DO_EPI){
      float part[4] = {0.f, 0.f, 0.f, 0.f};
      #pragma unroll
      for (int nt = 0; nt < 4; ++nt)
        #pragma unroll
        for (int r = 0; r < 4; ++r)
          part[r] = fmaf(fmaxf(acc[nt][r], 0.f), we2q[nt], part[r]);
      #pragma unroll
      for (int r = 0; r < 4; ++r) part[r] = row16_sum(part[r]);

      dotp += __shfl_xor(dotp, 16);
      dotp += __shfl_xor(dotp, 32);
      float dj = __shfl(dotp, srcl);

      if (q < 4){
        int j2 = jbase + kg*4 + q;
        float ps = part[0];
        ps = (q == 1) ? part[1] : ps;
        ps = (q == 2) ? part[2] : ps;
        ps = (q == 3) ? part[3] : ps;
        float cosv = dj * invni * s_invn[j2];
        float ev   = ps + be2v + s_prior[j2];
        lrowg[j2] = (j2 == i) ? spsl : fmaf(spss, cosv, ev);
      }
    } else {
      float vsum = acc[0][0] + acc[1][1] + acc[2][2] + acc[3][3] + dotp;
      keepf(vsum);
      if (q < 4){
        int j2 = jbase + kg*4 + q;
        lrowg[j2] = vsum;
      }
    }
  }
}

#define ABL_ARGS const float* hg, const float* pvec, const float* invn, \
    const short* wa_bf, const float* wjf, const float* wpf, const float* coords, \
    const float* We2, const float* be2, const float* sl, const float* ps, \
    const float* ss, float* logits
#define ABL_PASS hg, pvec, invn, wa_bf, wjf, wpf, coords, We2, be2, sl, ps, ss, logits

// distinctly-named probe kernels (rocprof attribution)
__global__ __launch_bounds__(512) void p_setup (ABL_ARGS){ abl_body<0 >(ABL_PASS); }
__global__ __launch_bounds__(512) void p_noload(ABL_ARGS){ abl_body<30>(ABL_PASS); }
__global__ __launch_bounds__(512) void p_nofeat(ABL_ARGS){ abl_body<29>(ABL_PASS); }
__global__ __launch_bounds__(512) void p_nomfma(ABL_ARGS){ abl_body<27>(ABL_PASS); }
__global__ __launch_bounds__(512) void p_noepi (ABL_ARGS){ abl_body<23>(ABL_PASS); }
__global__ __launch_bounds__(512) void p_lds   (ABL_ARGS){ abl_body<63>(ABL_PASS); }
__global__ __launch_bounds__(512) void p_full  (ABL_ARGS){ abl_body<31>(ABL_PASS); }

// ---------------- Kernel S: row softmax logits -> unsym ----------------
__global__ __launch_bounds__(256) void k_soft(
    const float* __restrict__ logits, const float* __restrict__ s_tp,
    float* __restrict__ unsym){
  int blk = blockIdx.x;
  int tid = threadIdx.x;
  int lane = tid & 63, w = tid >> 6;
  float invt = 1.f / (softplusf(s_tp[0]) + 1e-4f);

  const float* row = logits + (size_t)blk * NN;
  float2 v = *(const float2*)(row + tid*2);

  __shared__ float red[8];
  float m1 = fmaxf(v.x, v.y);
  #pragma unroll
  for (int msk = 1; msk < 64; msk <<= 1) m1 = fmaxf(m1, __shfl_xor(m1, msk));
  if (lane == 0) red[w] = m1;
  __syncthreads();
  m1 = fmaxf(fmaxf(red[0], red[1]), fmaxf(red[2], red[3]));

  float e0 = expf((v.x - m1) * invt);
  float e1 = expf((v.y - m1) * invt);
  float se = e0 + e1;
  #pragma unroll
  for (int msk = 1; msk < 64; msk <<= 1) se += __shfl_xor(se, msk);
  if (lane == 0) red[4 + w] = se;
  __syncthreads();
  se = red[4] + red[5] + red[6] + red[7];
  float inv_se = 1.f / se;

  float* urow = unsym + (size_t)blk * NN;
  *(float2*)(urow + tid*2) = (float2){e0 * inv_se, e1 * inv_se};
}

// ---------------- Kernel D: symmetrize + renormalize ----------------
__global__ __launch_bounds__(256) void k_sym(
    const float* __restrict__ u, float* __restrict__ out){
  int blk = blockIdx.x;
  int b = blk >> 9, i = blk & (NN-1);
  int tid = threadIdx.x;
  const float* urow = u + (size_t)(b*NN + i) * NN;
  float v0, v1, rs;
  {
    int j0 = tid, j1 = tid + 256;
    float a1 = urow[j0];
    float a2 = u[(size_t)(b*NN + j0) * NN + i];
    v0 = 0.5f*(a1 + a2);
    float a3 = urow[j1];
    float a4 = u[(size_t)(b*NN + j1) * NN + i];
    v1 = 0.5f*(a3 + a4);
    rs = v0 + v1;
  }
  int lane = tid & 63, w = tid >> 6;
  #pragma unroll
  for (int msk = 1; msk < 64; msk <<= 1) rs += __shfl_xor(rs, msk);
  __shared__ float red[4];
  if (lane == 0) red[w] = rs;
  __syncthreads();
  rs = red[0] + red[1] + red[2] + red[3];
  float inv = 1.f / fmaxf(rs, 1e-6f);
  float* orow = out + (size_t)(b*NN + i) * NN;
  orow[tid]       = v0 * inv;
  orow[tid + 256] = v1 * inv;
}

extern "C" void kernel_launch(void* const* d_in, const int* in_sizes, int n_in,
                              void* d_out, int out_size, void* d_ws, size_t ws_size,
                              hipStream_t stream){
  const float* x      = (const float*)d_in[0];
  const float* mask   = (const float*)d_in[1];
  const float* sctx   = (const float*)d_in[2];
  const float* coords = (const float*)d_in[3];
  const float* W1     = (const float*)d_in[4];
  const float* b1     = (const float*)d_in[5];
  const float* W2     = (const float*)d_in[6];
  const float* b2     = (const float*)d_in[7];
  const float* We1    = (const float*)d_in[8];
  const float* be1    = (const float*)d_in[9];
  const float* We2    = (const float*)d_in[10];
  const float* be2    = (const float*)d_in[11];
  const float* sl     = (const float*)d_in[12];
  const float* ps     = (const float*)d_in[13];
  const float* ss     = (const float*)d_in[14];
  const float* tp     = (const float*)d_in[15];

  float* ws     = (float*)d_ws;
  float* hgp    = ws + OFF_H;
  float* pvecp  = ws + OFF_PVEC;
  float* invnp  = ws + OFF_INVN;
  short* wabfp  = (short*)(ws + OFF_WA);
  float* wjfp   = ws + OFF_WJF;
  float* wpfp   = ws + OFF_WPF;
  float* unsym  = ws + OFF_UNSYM;
  float* logit  = ws + OFF_LOGIT;
  float* out    = (float*)d_out;

  k_front <<<304, 256, 0, stream>>>(x, mask, sctx, W1, b1, W2, b2, We1, be1,
                                    hgp, pvecp, invnp, wabfp, wjfp, wpfp);

  // ---- named ablation probes (scratch writes; p_full overwrites) ----
  p_setup <<<NB*NN, 512, 0, stream>>>(hgp, pvecp, invnp, wabfp, wjfp, wpfp,
                                      coords, We2, be2, sl, ps, ss, logit);
  p_noload<<<NB*NN, 512, 0, stream>>>(hgp, pvecp, invnp, wabfp, wjfp, wpfp,
                                      coords, We2, be2, sl, ps, ss, logit);
  p_nofeat<<<NB*NN, 512, 0, stream>>>(hgp, pvecp, invnp, wabfp, wjfp, wpfp,
                                      coords, We2, be2, sl, ps, ss, logit);
  p_nomfma<<<NB*NN, 512, 0, stream>>>(hgp, pvecp, invnp, wabfp, wjfp, wpfp,
                                      coords, We2, be2, sl, ps, ss, logit);
  p_noepi <<<NB*NN, 512, 0, stream>>>(hgp, pvecp, invnp, wabfp, wjfp, wpfp,
                                      coords, We2, be2, sl, ps, ss, logit);
  p_lds   <<<NB*NN, 512, 0, stream>>>(hgp, pvecp, invnp, wabfp, wjfp, wpfp,
                                      coords, We2, be2, sl, ps, ss, logit);
  // ---- real computation (runs last, defines correctness) ----
  p_full  <<<NB*NN, 512, 0, stream>>>(hgp, pvecp, invnp, wabfp, wjfp, wpfp,
                                      coords, We2, be2, sl, ps, ss, logit);

  k_soft  <<<NB*NN, 256, 0, stream>>>(logit, tp, unsym);
  k_sym   <<<NB*NN, 256, 0, stream>>>(unsym, out);
}

// Round 12
// 46.287 us; speedup vs baseline: 4.9705x; 4.9705x over previous
//
#include <hip/hip_runtime.h>
#include <hip/hip_bf16.h>
#include <math.h>

#define NB 2
#define NT 256
#define NN 512
#define NH 64
#define NS 8
#define NC 8

// workspace layout (float offsets)
#define OFF_H      0          // 65536  h f32
#define OFF_PVEC   65536      // 65536  pre_i + be1
#define OFF_HF16   131072     // 32768 dwords: h packed f16
#define OFF_HNF16  163840     // 32768 dwords: h*invnorm packed f16
#define OFF_WA16   196608     // 2048 floats = 4096 f16 (Wa frags)
#define OFF_WJF    198656     // 4096 floats (Wj, frag order)
#define OFF_WPF    202752     // 4096 floats (Wp, frag order)
#define OFF_GBASE  206848     // 524288: spss*cos
#define OFF_UNSYM  731136     // 524288
// total 1,255,424 floats ~= 5.0 MB

typedef __attribute__((ext_vector_type(8))) _Float16 h8;
typedef __attribute__((ext_vector_type(2))) __fp16 fp16x2;
typedef __attribute__((ext_vector_type(4))) float f32x4;
typedef __attribute__((ext_vector_type(4))) unsigned u4;
typedef __attribute__((ext_vector_type(2))) unsigned u2;

__device__ __forceinline__ float softplusf(float x){
  if (x > 20.f) return x;
  return log1pf(expf(x));
}

__device__ __forceinline__ unsigned pkh(float a, float b){
  fp16x2 h = __builtin_amdgcn_cvt_pkrtz(a, b);
  return __builtin_bit_cast(unsigned, h);
}

template<int CTRL>
__device__ __forceinline__ float dpp_addf(float x){
  int xi = __builtin_bit_cast(int, x);
  int yi = __builtin_amdgcn_update_dpp(0, xi, CTRL, 0xF, 0xF, true);
  return x + __builtin_bit_cast(float, yi);
}
__device__ __forceinline__ float row16_sum(float x){
  x = dpp_addf<0xB1>(x);    // lane^1
  x = dpp_addf<0x4E>(x);    // lane^2
  x = dpp_addf<0x141>(x);   // lane^7
  x = dpp_addf<0x140>(x);   // lane^15
  return x;
}

// ---------------- Kernel FRONT: stats + node MLP + weight prep ----------------
__global__ __launch_bounds__(256) void k_front(
    const float* __restrict__ x, const float* __restrict__ mask,
    const float* __restrict__ sctx,
    const float* __restrict__ W1, const float* __restrict__ b1,
    const float* __restrict__ W2, const float* __restrict__ b2,
    const float* __restrict__ We1, const float* __restrict__ be1,
    float* __restrict__ hg, float* __restrict__ pvec,
    unsigned* __restrict__ hf16, unsigned* __restrict__ hn16,
    short* __restrict__ wa16, float* __restrict__ wjf,
    float* __restrict__ wpf){
  int blk = blockIdx.x;
  int tid = threadIdx.x;

  if (blk >= 256){
    int pidx = (blk - 256)*256 + tid;        // 0..12287
    int e    = pidx & 7;
    int lane = (pidx >> 3) & 63;
    int frag = (pidx >> 9) & 7;              // ks*4+nt
    int nt = frag & 3, ks = frag >> 2;
    int kg = lane >> 4, q = lane & 15;
    int kk = ks*32 + kg*8 + e;
    int c  = nt*16 + q;
    if (pidx < 4096){
      _Float16 v = (_Float16)We1[(128 + kk)*NH + c];       // Wa rows 128..191
      wa16[pidx] = __builtin_bit_cast(short, v);
    } else if (pidx < 8192){
      wjf[pidx - 4096] = We1[(64 + kk)*NH + c];            // Wj rows 64..127
    } else {
      wpf[pidx - 8192] = We1[(192 + kk)*NH + c];           // Wp rows 192..255
    }
    return;
  }

  int b  = blk >> 7;
  int n0 = (blk & 127) * 4;

  // ---- stats: 4 nl x 64 ts ----
  int nl = tid & 3;
  int ts = tid >> 2;
  int n  = n0 + nl;

  float cnt = 0.f, sx = 0.f, sxx = 0.f;
  int lastt = 0;
  for (int t = ts*4; t < ts*4 + 4; ++t){
    int idx = (b*NT + t)*NN + n;
    float xv = x[idx];
    float mv = mask[idx];
    bool obs = (mv < 0.5f);
    if (obs){ cnt += 1.f; sx += xv; sxx += xv*xv; lastt = t; }
  }
  #pragma unroll
  for (int m = 4; m < 64; m <<= 1){
    cnt   += __shfl_xor(cnt,  m);
    sx    += __shfl_xor(sx,   m);
    sxx   += __shfl_xor(sxx,  m);
    lastt  = max(lastt, __shfl_xor(lastt, m));
  }
  int w = tid >> 6;
  __shared__ float r_cnt[4][4], r_sx[4][4], r_sxx[4][4];
  __shared__ int   r_lt[4][4];
  __shared__ float s_dyn[4][4];
  if ((tid & 63) < 4){
    r_cnt[w][nl] = cnt; r_sx[w][nl] = sx; r_sxx[w][nl] = sxx; r_lt[w][nl] = lastt;
  }
  __syncthreads();
  if (tid < 4){
    float c = 0.f, s1 = 0.f, s2 = 0.f; int lt = 0;
    #pragma unroll
    for (int ww = 0; ww < 4; ++ww){
      c  += r_cnt[ww][tid]; s1 += r_sx[ww][tid]; s2 += r_sxx[ww][tid];
      lt  = max(lt, r_lt[ww][tid]);
    }
    float cc   = fmaxf(c, 1.f);
    float mean = s1 / cc;
    float var  = s2 / cc - mean*mean;
    float stdv = sqrtf(fmaxf(var, 0.f) + 1e-6f);
    float last = x[(b*NT + lt)*NN + n0 + tid];
    float mr   = 1.f - c * (1.f/(float)NT);
    s_dyn[tid][0] = mean; s_dyn[tid][1] = stdv; s_dyn[tid][2] = last; s_dyn[tid][3] = mr;
  }
  __syncthreads();

  // ---- node MLP: wave w = node n0+w, lane c = channel ----
  int c = tid & 63;
  int gn = n0 + w;
  int bn = b*NN + gn;
  __shared__ float s_f[4][12];
  __shared__ float s_h1[4][64];
  __shared__ float s_h2[4][64];

  if (c < 4)       s_f[w][c] = s_dyn[w][c];
  else if (c < 12) s_f[w][c] = sctx[gn*NS + (c-4)];
  __syncthreads();

  float a = b1[c];
  #pragma unroll
  for (int k = 0; k < 12; ++k) a = fmaf(s_f[w][k], W1[k*NH + c], a);
  s_h1[w][c] = fmaxf(a, 0.f);
  __syncthreads();

  float a2 = b2[c];
  #pragma unroll 8
  for (int k = 0; k < 64; ++k) a2 = fmaf(s_h1[w][k], W2[k*NH + c], a2);
  a2 = fmaxf(a2, 0.f);

  float sq = a2*a2;
  #pragma unroll
  for (int m = 1; m < 64; m <<= 1) sq += __shfl_xor(sq, m);
  float inv = 1.f / fmaxf(sqrtf(sq), 1e-12f);

  s_h2[w][c] = a2;
  __syncthreads();

  float pi = be1[c];
  #pragma unroll 8
  for (int k = 0; k < 64; ++k) pi = fmaf(s_h2[w][k], We1[k*NH + c], pi);  // Wi

  hg  [bn*64 + c] = a2;
  pvec[bn*64 + c] = pi;
  if (c < 32){
    float e0 = s_h2[w][2*c], e1 = s_h2[w][2*c + 1];
    hf16[bn*32 + c] = pkh(e0, e1);
    hn16[bn*32 + c] = pkh(e0*inv, e1*inv);
  }
}

// ---------------- Kernel GRAM: gbase = spss * (hn . hn^T) via MFMA ----------
// grid (NB, 32, 4): block = 16 i x 128 j; 4 waves x 2 j-tiles.
__global__ __launch_bounds__(256) void k_gram(
    const unsigned* __restrict__ hn16, const float* __restrict__ s_ss,
    float* __restrict__ gbase){
  int b   = blockIdx.x;
  int i0  = blockIdx.y * 16;
  int jq  = blockIdx.z;
  int tid = threadIdx.x;
  int w   = tid >> 6;
  int lane = tid & 63;
  float spss = softplusf(s_ss[0]);

  const u4* hv = (const u4*)hn16;
  int arow = i0 + (lane & 15);
  u4 a0 = hv[(b*NN + arow)*8 + (lane >> 4)];
  u4 a1 = hv[(b*NN + arow)*8 + (lane >> 4) + 4];
  h8 A0 = __builtin_bit_cast(h8, a0);
  h8 A1 = __builtin_bit_cast(h8, a1);

  #pragma unroll
  for (int t = 0; t < 2; ++t){
    int j0 = (jq*8 + w*2 + t) * 16;
    int jrow = j0 + (lane & 15);
    u4 b0 = hv[(b*NN + jrow)*8 + (lane >> 4)];
    u4 b1 = hv[(b*NN + jrow)*8 + (lane >> 4) + 4];
    f32x4 acc = (f32x4){0.f, 0.f, 0.f, 0.f};
    acc = __builtin_amdgcn_mfma_f32_16x16x32_f16(A0, __builtin_bit_cast(h8, b0), acc, 0, 0, 0);
    acc = __builtin_amdgcn_mfma_f32_16x16x32_f16(A1, __builtin_bit_cast(h8, b1), acc, 0, 0, 0);
    #pragma unroll
    for (int r = 0; r < 4; ++r){
      int irow = i0 + (lane >> 4)*4 + r;
      gbase[(size_t)(b*NN + irow)*NN + j0 + (lane & 15)] = spss * acc[r];
    }
  }
}

// ---------------- Kernel LOGITS: pairwise MLP + logits + fused softmax ------
// grid NB*NN (block per (b,i)), 512 thr = 8 waves; wave: 4 j-tiles (w, w+8, ...).
// features f16: [|hi-hj| ; hj] (K=128), B = [Wa ; Wj + diag(hi)Wp] in LDS.
__global__ __launch_bounds__(512, 4) void k_logits(
    const float* __restrict__ hg, const float* __restrict__ pvec,
    const unsigned* __restrict__ hf16, const short* __restrict__ wa16,
    const float* __restrict__ wjf, const float* __restrict__ wpf,
    const float* __restrict__ coords, const float* __restrict__ We2,
    const float* __restrict__ be2, const float* __restrict__ gbase,
    const float* __restrict__ s_sl, const float* __restrict__ s_ps,
    const float* __restrict__ s_tp,
    float* __restrict__ unsym){
  int blk = blockIdx.x;
  int b = blk >> 9, i = blk & (NN-1);
  int tid  = threadIdx.x;
  int w    = tid >> 6;
  int lane = tid & 63;
  int q    = lane & 15;
  int kg   = lane >> 4;

  __shared__ __align__(16) float s_hi[64];
  __shared__ __align__(16) float s_pv[64];
  __shared__ __align__(16) float s_prior[NN];   // spps*prior (0 diag)
  __shared__ __align__(16) float s_gcos[NN];    // spss*cos
  __shared__ __align__(16) float lrow[NN];
  __shared__ __align__(16) unsigned lds_wa[2048];  // 8 frags x 64 lanes x 4 dw
  __shared__ __align__(16) unsigned lds_cw[2048];
  __shared__ __align__(16) unsigned s_hj[8][16*34 + 2]; // per-wave hj slice
  __shared__ float red[16];

  float spsl = softplusf(s_sl[0]);
  float spps = softplusf(s_ps[0]);
  float invt = 1.f / (softplusf(s_tp[0]) + 1e-4f);

  if (tid < 64){
    s_hi[tid] = hg  [(b*NN + i)*64 + tid];
    s_pv[tid] = pvec[(b*NN + i)*64 + tid];
  }
  {
    int j = tid;   // 512 threads, one j each
    float4 ci0 = *(const float4*)(coords + i*NC);
    float4 ci1 = *(const float4*)(coords + i*NC + 4);
    float4 cj0 = *(const float4*)(coords + j*NC);
    float4 cj1 = *(const float4*)(coords + j*NC + 4);
    float dd = 0.f;
    dd = fmaf(ci0.x-cj0.x, ci0.x-cj0.x, dd);
    dd = fmaf(ci0.y-cj0.y, ci0.y-cj0.y, dd);
    dd = fmaf(ci0.z-cj0.z, ci0.z-cj0.z, dd);
    dd = fmaf(ci0.w-cj0.w, ci0.w-cj0.w, dd);
    dd = fmaf(ci1.x-cj1.x, ci1.x-cj1.x, dd);
    dd = fmaf(ci1.y-cj1.y, ci1.y-cj1.y, dd);
    dd = fmaf(ci1.z-cj1.z, ci1.z-cj1.z, dd);
    dd = fmaf(ci1.w-cj1.w, ci1.w-cj1.w, dd);
    float dist = sqrtf(fmaxf(dd, 1e-12f));
    s_prior[j] = (j == i) ? 0.f : spps / (1.f + dist);
    s_gcos[j]  = gbase[(size_t)(b*NN + i)*NN + j];
  }
  __syncthreads();   // s_hi ready

  // build LDS B-frags: wa copy + cw = f16(Wj + diag(hi)*Wp); thread = (frag,lane2)
  {
    int frag = tid >> 6;          // 0..7 = ks*4+nt
    int l2   = tid & 63;
    const u4* wsrc = (const u4*)wa16;
    *(u4*)&lds_wa[(frag*64 + l2)*4] = wsrc[frag*64 + l2];

    int ch0 = (frag >> 2)*32 + (l2 >> 4)*8;   // k-channel base for this slot
    const float* wj = wjf + (frag*64 + l2)*8;
    const float* wp = wpf + (frag*64 + l2)*8;
    u4 u;
    #pragma unroll
    for (int d = 0; d < 4; ++d){
      float v0 = fmaf(s_hi[ch0 + 2*d],     wp[2*d],     wj[2*d]);
      float v1 = fmaf(s_hi[ch0 + 2*d + 1], wp[2*d + 1], wj[2*d + 1]);
      u[d] = pkh(v0, v1);
    }
    *(u4*)&lds_cw[(frag*64 + l2)*4] = u;
  }

  // per-lane hi packed f16 (matches A-frag k-mapping)
  const u4* hfv = (const u4*)hf16;
  u4 hi0 = hfv[(b*NN + i)*8 + kg];
  u4 hi1 = hfv[(b*NN + i)*8 + kg + 4];

  float pv4[4], we2q[4];
  #pragma unroll
  for (int nt = 0; nt < 4; ++nt){
    pv4[nt]  = pvec[(b*NN + i)*64 + nt*16 + q];
    we2q[nt] = We2[nt*16 + q];
  }
  float be2v = be2[0];
  __syncthreads();   // lds_wa / lds_cw ready

  unsigned* slice = &s_hj[w][0];
  const u4 absm = (u4){0x7fff7fffu, 0x7fff7fffu, 0x7fff7fffu, 0x7fff7fffu};

  #pragma unroll
  for (int s = 0; s < 4; ++s){
    int it = w + s*8;
    int jbase = it * 16;

    // stage hj tile (16 rows x 64 ch f16 = 2 KB) coalesced -> wave-private LDS
    {
      int r8 = lane >> 3, c8 = lane & 7;
      u4 g0 = *(const u4*)((const unsigned*)hf16 + (size_t)(b*NN + jbase + r8)*32 + c8*4);
      u4 g1 = *(const u4*)((const unsigned*)hf16 + (size_t)(b*NN + jbase + 8 + r8)*32 + c8*4);
      unsigned* p0 = slice + r8*34 + c8*4;
      unsigned* p1 = slice + (8 + r8)*34 + c8*4;
      u2 t;
      t.x = g0.x; t.y = g0.y; *(u2*)p0 = t;
      t.x = g0.z; t.y = g0.w; *(u2*)(p0 + 2) = t;
      t.x = g1.x; t.y = g1.y; *(u2*)p1 = t;
      t.x = g1.z; t.y = g1.w; *(u2*)(p1 + 2) = t;
    }

    // read this lane's hj fragment (row q, k-slices kg)
    u4 hj0, hj1;
    {
      unsigned* rp = slice + q*34 + kg*4;
      u2 a0 = *(u2*)rp;
      u2 a1 = *(u2*)(rp + 2);
      u2 b0 = *(u2*)(rp + 16);
      u2 b1 = *(u2*)(rp + 18);
      hj0.x = a0.x; hj0.y = a0.y; hj0.z = a1.x; hj0.w = a1.y;
      hj1.x = b0.x; hj1.y = b0.y; hj1.z = b1.x; hj1.w = b1.y;
    }

    // features: d = |hi-hj| (packed f16 sub + abs mask); hj used raw
    h8 dh0 = __builtin_bit_cast(h8, hi0) - __builtin_bit_cast(h8, hj0);
    h8 dh1 = __builtin_bit_cast(h8, hi1) - __builtin_bit_cast(h8, hj1);
    h8 af0 = __builtin_bit_cast(h8, __builtin_bit_cast(u4, dh0) & absm);
    h8 af1 = __builtin_bit_cast(h8, __builtin_bit_cast(u4, dh1) & absm);
    h8 af2 = __builtin_bit_cast(h8, hj0);
    h8 af3 = __builtin_bit_cast(h8, hj1);

    f32x4 acc[4];
    #pragma unroll
    for (int nt = 0; nt < 4; ++nt)
      acc[nt] = (f32x4){pv4[nt], pv4[nt], pv4[nt], pv4[nt]};
    #pragma unroll
    for (int nt = 0; nt < 4; ++nt){
      h8 wA0 = __builtin_bit_cast(h8, *(const u4*)&lds_wa[((0*4 + nt)*64 + lane)*4]);
      h8 wA1 = __builtin_bit_cast(h8, *(const u4*)&lds_wa[((1*4 + nt)*64 + lane)*4]);
      h8 wC0 = __builtin_bit_cast(h8, *(const u4*)&lds_cw[((0*4 + nt)*64 + lane)*4]);
      h8 wC1 = __builtin_bit_cast(h8, *(const u4*)&lds_cw[((1*4 + nt)*64 + lane)*4]);
      acc[nt] = __builtin_amdgcn_mfma_f32_16x16x32_f16(af0, wA0, acc[nt], 0, 0, 0);
      acc[nt] = __builtin_amdgcn_mfma_f32_16x16x32_f16(af1, wA1, acc[nt], 0, 0, 0);
      acc[nt] = __builtin_amdgcn_mfma_f32_16x16x32_f16(af2, wC0, acc[nt], 0, 0, 0);
      acc[nt] = __builtin_amdgcn_mfma_f32_16x16x32_f16(af3, wC1, acc[nt], 0, 0, 0);
    }

    // epilogue: relu + We2 dot, DPP 16-lane reduce, assemble logit
    float part[4] = {0.f, 0.f, 0.f, 0.f};
    #pragma unroll
    for (int nt = 0; nt < 4; ++nt)
      #pragma unroll
      for (int r = 0; r < 4; ++r)
        part[r] = fmaf(fmaxf(acc[nt][r], 0.f), we2q[nt], part[r]);
    #pragma unroll
    for (int r = 0; r < 4; ++r) part[r] = row16_sum(part[r]);

    if (q < 4){
      int j2 = jbase + kg*4 + q;
      float ps2 = part[0];
      ps2 = (q == 1) ? part[1] : ps2;
      ps2 = (q == 2) ? part[2] : ps2;
      ps2 = (q == 3) ? part[3] : ps2;
      float lg = ps2 + be2v + s_prior[j2] + s_gcos[j2];
      lrow[j2] = (j2 == i) ? spsl : lg;
    }
  }
  __syncthreads();

  // fused row softmax (512 threads, 1 elem each)
  float v = lrow[tid];
  float m1 = v;
  #pragma unroll
  for (int msk = 1; msk < 64; msk <<= 1) m1 = fmaxf(m1, __shfl_xor(m1, msk));
  if (lane == 0) red[w] = m1;
  __syncthreads();
  m1 = red[0];
  #pragma unroll
  for (int ww = 1; ww < 8; ++ww) m1 = fmaxf(m1, red[ww]);

  float e = expf((v - m1) * invt);
  float se = e;
  #pragma unroll
  for (int msk = 1; msk < 64; msk <<= 1) se += __shfl_xor(se, msk);
  if (lane == 0) red[8 + w] = se;
  __syncthreads();
  se = red[8];
  #pragma unroll
  for (int ww = 1; ww < 8; ++ww) se += red[8 + ww];

  unsym[(size_t)(b*NN + i)*NN + tid] = e / se;
}

// ---------------- Kernel D: symmetrize + renormalize ----------------
__global__ __launch_bounds__(256) void k_sym(
    const float* __restrict__ u, float* __restrict__ out){
  int blk = blockIdx.x;
  int b = blk >> 9, i = blk & (NN-1);
  int tid = threadIdx.x;
  const float* urow = u + (size_t)(b*NN + i) * NN;
  float v0, v1, rs;
  {
    int j0 = tid, j1 = tid + 256;
    float a1 = urow[j0];
    float a2 = u[(size_t)(b*NN + j0) * NN + i];
    v0 = 0.5f*(a1 + a2);
    float a3 = urow[j1];
    float a4 = u[(size_t)(b*NN + j1) * NN + i];
    v1 = 0.5f*(a3 + a4);
    rs = v0 + v1;
  }
  int lane = tid & 63, w = tid >> 6;
  #pragma unroll
  for (int msk = 1; msk < 64; msk <<= 1) rs += __shfl_xor(rs, msk);
  __shared__ float red[4];
  if (lane == 0) red[w] = rs;
  __syncthreads();
  rs = red[0] + red[1] + red[2] + red[3];
  float inv = 1.f / fmaxf(rs, 1e-6f);
  float* orow = out + (size_t)(b*NN + i) * NN;
  orow[tid]       = v0 * inv;
  orow[tid + 256] = v1 * inv;
}

extern "C" void kernel_launch(void* const* d_in, const int* in_sizes, int n_in,
                              void* d_out, int out_size, void* d_ws, size_t ws_size,
                              hipStream_t stream){
  const float* x      = (const float*)d_in[0];
  const float* mask   = (const float*)d_in[1];
  const float* sctx   = (const float*)d_in[2];
  const float* coords = (const float*)d_in[3];
  const float* W1     = (const float*)d_in[4];
  const float* b1     = (const float*)d_in[5];
  const float* W2     = (const float*)d_in[6];
  const float* b2     = (const float*)d_in[7];
  const float* We1    = (const float*)d_in[8];
  const float* be1    = (const float*)d_in[9];
  const float* We2    = (const float*)d_in[10];
  const float* be2    = (const float*)d_in[11];
  const float* sl     = (const float*)d_in[12];
  const float* ps     = (const float*)d_in[13];
  const float* ss     = (const float*)d_in[14];
  const float* tp     = (const float*)d_in[15];

  float*    ws    = (float*)d_ws;
  float*    hgp   = ws + OFF_H;
  float*    pvecp = ws + OFF_PVEC;
  unsigned* hf16p = (unsigned*)(ws + OFF_HF16);
  unsigned* hn16p = (unsigned*)(ws + OFF_HNF16);
  short*    wa16p = (short*)(ws + OFF_WA16);
  float*    wjfp  = ws + OFF_WJF;
  float*    wpfp  = ws + OFF_WPF;
  float*    gbase = ws + OFF_GBASE;
  float*    unsym = ws + OFF_UNSYM;
  float*    out   = (float*)d_out;

  k_front <<<304, 256, 0, stream>>>(x, mask, sctx, W1, b1, W2, b2, We1, be1,
                                    hgp, pvecp, hf16p, hn16p, wa16p, wjfp, wpfp);
  k_gram  <<<dim3(NB, 32, 4), 256, 0, stream>>>(hn16p, ss, gbase);
  k_logits<<<NB*NN, 512, 0, stream>>>(hgp, pvecp, hf16p, wa16p, wjfp, wpfp,
                                      coords, We2, be2, gbase, sl, ps, tp, unsym);
  k_sym   <<<NB*NN, 256, 0, stream>>>(unsym, out);
}

// Round 13
// 43.614 us; speedup vs baseline: 5.2752x; 1.0613x over previous
//
#include <hip/hip_runtime.h>
#include <hip/hip_bf16.h>
#include <math.h>

#define NB 2
#define NT 256
#define NN 512
#define NH 64
#define NS 8
#define NC 8

// workspace layout (float offsets)
#define OFF_H      0          // 65536  h f32
#define OFF_PVEC   65536      // 65536  pre_i + be1
#define OFF_HF16   131072     // 32768 dwords: h packed f16
#define OFF_HNF16  163840     // 32768 dwords: h*invnorm packed f16
#define OFF_WA16   196608     // 2048 floats = 4096 f16 (Wa frags)
#define OFF_WJF    198656     // 4096 floats (Wj, frag order)
#define OFF_WPF    202752     // 4096 floats (Wp, frag order)
#define OFF_GEXT   206848     // 524288: be2 + spss*cos + spps*prior
#define OFF_UNSYM  731136     // 524288

typedef __attribute__((ext_vector_type(8))) _Float16 h8;
typedef __attribute__((ext_vector_type(2))) __fp16 fp16x2;
typedef __attribute__((ext_vector_type(4))) float f32x4;
typedef __attribute__((ext_vector_type(4))) unsigned u4;
typedef __attribute__((ext_vector_type(2))) unsigned u2;

__device__ __forceinline__ float softplusf(float x){
  if (x > 20.f) return x;
  return log1pf(expf(x));
}

__device__ __forceinline__ unsigned pkh(float a, float b){
  fp16x2 h = __builtin_amdgcn_cvt_pkrtz(a, b);
  return __builtin_bit_cast(unsigned, h);
}

template<int CTRL>
__device__ __forceinline__ float dpp_addf(float x){
  int xi = __builtin_bit_cast(int, x);
  int yi = __builtin_amdgcn_update_dpp(0, xi, CTRL, 0xF, 0xF, true);
  return x + __builtin_bit_cast(float, yi);
}
__device__ __forceinline__ float row16_sum(float x){
  x = dpp_addf<0xB1>(x);    // lane^1
  x = dpp_addf<0x4E>(x);    // lane^2
  x = dpp_addf<0x141>(x);   // lane^7
  x = dpp_addf<0x140>(x);   // lane^15
  return x;
}

// ---------------- Kernel FRONT: stats + node MLP + weight prep ----------------
__global__ __launch_bounds__(256) void k_front(
    const float* __restrict__ x, const float* __restrict__ mask,
    const float* __restrict__ sctx,
    const float* __restrict__ W1, const float* __restrict__ b1,
    const float* __restrict__ W2, const float* __restrict__ b2,
    const float* __restrict__ We1, const float* __restrict__ be1,
    float* __restrict__ hg, float* __restrict__ pvec,
    unsigned* __restrict__ hf16, unsigned* __restrict__ hn16,
    short* __restrict__ wa16, float* __restrict__ wjf,
    float* __restrict__ wpf){
  int blk = blockIdx.x;
  int tid = threadIdx.x;

  if (blk >= 256){
    int pidx = (blk - 256)*256 + tid;        // 0..12287
    int e    = pidx & 7;
    int lane = (pidx >> 3) & 63;
    int frag = (pidx >> 9) & 7;              // ks*4+nt
    int nt = frag & 3, ks = frag >> 2;
    int kg = lane >> 4, q = lane & 15;
    int kk = ks*32 + kg*8 + e;
    int c  = nt*16 + q;
    if (pidx < 4096){
      _Float16 v = (_Float16)We1[(128 + kk)*NH + c];       // Wa rows 128..191
      wa16[pidx] = __builtin_bit_cast(short, v);
    } else if (pidx < 8192){
      wjf[pidx - 4096] = We1[(64 + kk)*NH + c];            // Wj rows 64..127
    } else {
      wpf[pidx - 8192] = We1[(192 + kk)*NH + c];           // Wp rows 192..255
    }
    return;
  }

  int b  = blk >> 7;
  int n0 = (blk & 127) * 4;

  // ---- stats: 4 nl x 64 ts ----
  int nl = tid & 3;
  int ts = tid >> 2;
  int n  = n0 + nl;

  float cnt = 0.f, sx = 0.f, sxx = 0.f;
  int lastt = 0;
  for (int t = ts*4; t < ts*4 + 4; ++t){
    int idx = (b*NT + t)*NN + n;
    float xv = x[idx];
    float mv = mask[idx];
    bool obs = (mv < 0.5f);
    if (obs){ cnt += 1.f; sx += xv; sxx += xv*xv; lastt = t; }
  }
  #pragma unroll
  for (int m = 4; m < 64; m <<= 1){
    cnt   += __shfl_xor(cnt,  m);
    sx    += __shfl_xor(sx,   m);
    sxx   += __shfl_xor(sxx,  m);
    lastt  = max(lastt, __shfl_xor(lastt, m));
  }
  int w = tid >> 6;
  __shared__ float r_cnt[4][4], r_sx[4][4], r_sxx[4][4];
  __shared__ int   r_lt[4][4];
  __shared__ float s_dyn[4][4];
  if ((tid & 63) < 4){
    r_cnt[w][nl] = cnt; r_sx[w][nl] = sx; r_sxx[w][nl] = sxx; r_lt[w][nl] = lastt;
  }
  __syncthreads();
  if (tid < 4){
    float c = 0.f, s1 = 0.f, s2 = 0.f; int lt = 0;
    #pragma unroll
    for (int ww = 0; ww < 4; ++ww){
      c  += r_cnt[ww][tid]; s1 += r_sx[ww][tid]; s2 += r_sxx[ww][tid];
      lt  = max(lt, r_lt[ww][tid]);
    }
    float cc   = fmaxf(c, 1.f);
    float mean = s1 / cc;
    float var  = s2 / cc - mean*mean;
    float stdv = sqrtf(fmaxf(var, 0.f) + 1e-6f);
    float last = x[(b*NT + lt)*NN + n0 + tid];
    float mr   = 1.f - c * (1.f/(float)NT);
    s_dyn[tid][0] = mean; s_dyn[tid][1] = stdv; s_dyn[tid][2] = last; s_dyn[tid][3] = mr;
  }
  __syncthreads();

  // ---- node MLP: wave w = node n0+w, lane c = channel ----
  int c = tid & 63;
  int gn = n0 + w;
  int bn = b*NN + gn;
  __shared__ float s_f[4][12];
  __shared__ float s_h1[4][64];
  __shared__ float s_h2[4][64];

  if (c < 4)       s_f[w][c] = s_dyn[w][c];
  else if (c < 12) s_f[w][c] = sctx[gn*NS + (c-4)];
  __syncthreads();

  float a = b1[c];
  #pragma unroll
  for (int k = 0; k < 12; ++k) a = fmaf(s_f[w][k], W1[k*NH + c], a);
  s_h1[w][c] = fmaxf(a, 0.f);
  __syncthreads();

  float a2 = b2[c];
  #pragma unroll 8
  for (int k = 0; k < 64; ++k) a2 = fmaf(s_h1[w][k], W2[k*NH + c], a2);
  a2 = fmaxf(a2, 0.f);

  float sq = a2*a2;
  #pragma unroll
  for (int m = 1; m < 64; m <<= 1) sq += __shfl_xor(sq, m);
  float inv = 1.f / fmaxf(sqrtf(sq), 1e-12f);

  s_h2[w][c] = a2;
  __syncthreads();

  float pi = be1[c];
  #pragma unroll 8
  for (int k = 0; k < 64; ++k) pi = fmaf(s_h2[w][k], We1[k*NH + c], pi);  // Wi

  hg  [bn*64 + c] = a2;
  pvec[bn*64 + c] = pi;
  if (c < 32){
    float e0 = s_h2[w][2*c], e1 = s_h2[w][2*c + 1];
    hf16[bn*32 + c] = pkh(e0, e1);
    hn16[bn*32 + c] = pkh(e0*inv, e1*inv);
  }
}

// ---------------- Kernel EXTRA: gext = be2 + spss*cos + spps*prior ----------
// grid (NB, 32, 4): block = 16 i x 128 j; 4 waves x 2 j-tiles.
__global__ __launch_bounds__(256) void k_extra(
    const unsigned* __restrict__ hn16, const float* __restrict__ coords,
    const float* __restrict__ s_ss, const float* __restrict__ s_ps,
    const float* __restrict__ be2, float* __restrict__ gext){
  int b   = blockIdx.x;
  int i0  = blockIdx.y * 16;
  int jq  = blockIdx.z;
  int tid = threadIdx.x;
  int w   = tid >> 6;
  int lane = tid & 63;
  float spss = softplusf(s_ss[0]);
  float spps = softplusf(s_ps[0]);
  float be2v = be2[0];

  const u4* hv = (const u4*)hn16;
  int arow = i0 + (lane & 15);
  u4 a0 = hv[(b*NN + arow)*8 + (lane >> 4)];
  u4 a1 = hv[(b*NN + arow)*8 + (lane >> 4) + 4];
  h8 A0 = __builtin_bit_cast(h8, a0);
  h8 A1 = __builtin_bit_cast(h8, a1);

  #pragma unroll
  for (int t = 0; t < 2; ++t){
    int j0 = (jq*8 + w*2 + t) * 16;
    int jrow = j0 + (lane & 15);
    u4 b0 = hv[(b*NN + jrow)*8 + (lane >> 4)];
    u4 b1 = hv[(b*NN + jrow)*8 + (lane >> 4) + 4];
    f32x4 acc = (f32x4){0.f, 0.f, 0.f, 0.f};
    acc = __builtin_amdgcn_mfma_f32_16x16x32_f16(A0, __builtin_bit_cast(h8, b0), acc, 0, 0, 0);
    acc = __builtin_amdgcn_mfma_f32_16x16x32_f16(A1, __builtin_bit_cast(h8, b1), acc, 0, 0, 0);

    int jc = j0 + (lane & 15);
    float4 cj0 = *(const float4*)(coords + jc*NC);
    float4 cj1 = *(const float4*)(coords + jc*NC + 4);
    #pragma unroll
    for (int r = 0; r < 4; ++r){
      int irow = i0 + (lane >> 4)*4 + r;
      float4 ci0 = *(const float4*)(coords + irow*NC);
      float4 ci1 = *(const float4*)(coords + irow*NC + 4);
      float dd = 0.f;
      dd = fmaf(ci0.x-cj0.x, ci0.x-cj0.x, dd);
      dd = fmaf(ci0.y-cj0.y, ci0.y-cj0.y, dd);
      dd = fmaf(ci0.z-cj0.z, ci0.z-cj0.z, dd);
      dd = fmaf(ci0.w-cj0.w, ci0.w-cj0.w, dd);
      dd = fmaf(ci1.x-cj1.x, ci1.x-cj1.x, dd);
      dd = fmaf(ci1.y-cj1.y, ci1.y-cj1.y, dd);
      dd = fmaf(ci1.z-cj1.z, ci1.z-cj1.z, dd);
      dd = fmaf(ci1.w-cj1.w, ci1.w-cj1.w, dd);
      float dist  = sqrtf(fmaxf(dd, 1e-12f));
      float prior = (irow == jc) ? 0.f : spps / (1.f + dist);
      gext[(size_t)(b*NN + irow)*NN + jc] = fmaf(spss, acc[r], be2v + prior);
    }
  }
}

// ---------------- Kernel LOGITS: 2 i-rows per block + fused softmax ----------
// grid NB*NN/2 (block = (b, i-pair)), 512 thr = 8 waves; wave: 4 j-tiles.
// features f16: [|hi-hj| ; hj] (K=128), B = [Wa ; Wj + diag(hi)Wp] in LDS.
__global__ __launch_bounds__(512, 4) void k_logits(
    const float* __restrict__ hg, const float* __restrict__ pvec,
    const unsigned* __restrict__ hf16, const short* __restrict__ wa16,
    const float* __restrict__ wjf, const float* __restrict__ wpf,
    const float* __restrict__ We2, const float* __restrict__ gext,
    const float* __restrict__ s_sl, const float* __restrict__ s_tp,
    float* __restrict__ unsym){
  int blk = blockIdx.x;
  int b  = blk >> 8;
  int ip = (blk & 255) * 2;          // rows ip, ip+1
  int tid  = threadIdx.x;
  int w    = tid >> 6;
  int lane = tid & 63;
  int q    = lane & 15;
  int kg   = lane >> 4;

  __shared__ __align__(16) float s_hi[2][64];
  __shared__ __align__(16) float s_ext[2][NN];
  __shared__ __align__(16) float lrow[2][NN];
  __shared__ __align__(16) unsigned lds_wa[2048];     // 8 frags x 64 x 4dw
  __shared__ __align__(16) unsigned lds_cw[2][2048];
  __shared__ __align__(16) unsigned s_hj[8][16*34 + 2];
  __shared__ float red[32];

  float spsl = softplusf(s_sl[0]);
  float invt = 1.f / (softplusf(s_tp[0]) + 1e-4f);

  if (tid < 128)
    s_hi[tid >> 6][tid & 63] = hg[(b*NN + ip + (tid >> 6))*64 + (tid & 63)];
  #pragma unroll
  for (int r = 0; r < 2; ++r)
    s_ext[r][tid] = gext[(size_t)(b*NN + ip + r)*NN + tid];
  __syncthreads();   // s_hi ready

  // B-frags in LDS: wa copy + per-row cw = f16(Wj + diag(hi)*Wp)
  {
    int frag = tid >> 6;          // 0..7 = ks*4+nt
    int l2   = tid & 63;
    const u4* wsrc = (const u4*)wa16;
    *(u4*)&lds_wa[(frag*64 + l2)*4] = wsrc[frag*64 + l2];

    int ch0 = (frag >> 2)*32 + (l2 >> 4)*8;
    const float* wj = wjf + (frag*64 + l2)*8;
    const float* wp = wpf + (frag*64 + l2)*8;
    #pragma unroll
    for (int r = 0; r < 2; ++r){
      u4 u;
      #pragma unroll
      for (int d = 0; d < 4; ++d){
        float v0 = fmaf(s_hi[r][ch0 + 2*d],     wp[2*d],     wj[2*d]);
        float v1 = fmaf(s_hi[r][ch0 + 2*d + 1], wp[2*d + 1], wj[2*d + 1]);
        u[d] = pkh(v0, v1);
      }
      *(u4*)&lds_cw[r][(frag*64 + l2)*4] = u;
    }
  }

  // per-lane hi packed f16 for both rows
  const u4* hfv = (const u4*)hf16;
  u4 hiA[2][2];
  #pragma unroll
  for (int r = 0; r < 2; ++r){
    hiA[r][0] = hfv[(b*NN + ip + r)*8 + kg];
    hiA[r][1] = hfv[(b*NN + ip + r)*8 + kg + 4];
  }

  float pv4[2][4], we2q[4];
  #pragma unroll
  for (int nt = 0; nt < 4; ++nt){
    #pragma unroll
    for (int r = 0; r < 2; ++r)
      pv4[r][nt] = pvec[(b*NN + ip + r)*64 + nt*16 + q];
    we2q[nt] = We2[nt*16 + q];
  }
  __syncthreads();   // lds_wa / lds_cw ready

  unsigned* slice = &s_hj[w][0];
  const u4 absm = (u4){0x7fff7fffu, 0x7fff7fffu, 0x7fff7fffu, 0x7fff7fffu};

  #pragma unroll
  for (int s = 0; s < 4; ++s){
    int it = w + s*8;
    int jbase = it * 16;

    // stage hj tile (16 rows x 64 ch f16 = 2 KB) coalesced -> wave-private LDS
    {
      int r8 = lane >> 3, c8 = lane & 7;
      u4 g0 = *(const u4*)((const unsigned*)hf16 + (size_t)(b*NN + jbase + r8)*32 + c8*4);
      u4 g1 = *(const u4*)((const unsigned*)hf16 + (size_t)(b*NN + jbase + 8 + r8)*32 + c8*4);
      unsigned* p0 = slice + r8*34 + c8*4;
      unsigned* p1 = slice + (8 + r8)*34 + c8*4;
      u2 t;
      t.x = g0.x; t.y = g0.y; *(u2*)p0 = t;
      t.x = g0.z; t.y = g0.w; *(u2*)(p0 + 2) = t;
      t.x = g1.x; t.y = g1.y; *(u2*)p1 = t;
      t.x = g1.z; t.y = g1.w; *(u2*)(p1 + 2) = t;
    }

    // this lane's hj fragment (row q, k-slices kg)
    u4 hj0, hj1;
    {
      unsigned* rp = slice + q*34 + kg*4;
      u2 a0 = *(u2*)rp;
      u2 a1 = *(u2*)(rp + 2);
      u2 b0 = *(u2*)(rp + 16);
      u2 b1 = *(u2*)(rp + 18);
      hj0.x = a0.x; hj0.y = a0.y; hj0.z = a1.x; hj0.w = a1.y;
      hj1.x = b0.x; hj1.y = b0.y; hj1.z = b1.x; hj1.w = b1.y;
    }
    h8 hjv0 = __builtin_bit_cast(h8, hj0);
    h8 hjv1 = __builtin_bit_cast(h8, hj1);

    // shared B-frag reads (wa) once; cw per row
    f32x4 acc[2][4];
    #pragma unroll
    for (int r = 0; r < 2; ++r)
      #pragma unroll
      for (int nt = 0; nt < 4; ++nt)
        acc[r][nt] = (f32x4){pv4[r][nt], pv4[r][nt], pv4[r][nt], pv4[r][nt]};

    #pragma unroll
    for (int nt = 0; nt < 4; ++nt){
      h8 wA0 = __builtin_bit_cast(h8, *(const u4*)&lds_wa[((0*4 + nt)*64 + lane)*4]);
      h8 wA1 = __builtin_bit_cast(h8, *(const u4*)&lds_wa[((1*4 + nt)*64 + lane)*4]);
      #pragma unroll
      for (int r = 0; r < 2; ++r){
        h8 dh0 = __builtin_bit_cast(h8, hiA[r][0]) - hjv0;
        h8 dh1 = __builtin_bit_cast(h8, hiA[r][1]) - hjv1;
        h8 af0 = __builtin_bit_cast(h8, __builtin_bit_cast(u4, dh0) & absm);
        h8 af1 = __builtin_bit_cast(h8, __builtin_bit_cast(u4, dh1) & absm);
        h8 wC0 = __builtin_bit_cast(h8, *(const u4*)&lds_cw[r][((0*4 + nt)*64 + lane)*4]);
        h8 wC1 = __builtin_bit_cast(h8, *(const u4*)&lds_cw[r][((1*4 + nt)*64 + lane)*4]);
        acc[r][nt] = __builtin_amdgcn_mfma_f32_16x16x32_f16(af0, wA0, acc[r][nt], 0, 0, 0);
        acc[r][nt] = __builtin_amdgcn_mfma_f32_16x16x32_f16(af1, wA1, acc[r][nt], 0, 0, 0);
        acc[r][nt] = __builtin_amdgcn_mfma_f32_16x16x32_f16(hjv0, wC0, acc[r][nt], 0, 0, 0);
        acc[r][nt] = __builtin_amdgcn_mfma_f32_16x16x32_f16(hjv1, wC1, acc[r][nt], 0, 0, 0);
      }
    }

    // epilogue per row: relu + We2 dot, DPP 16-lane reduce
    #pragma unroll
    for (int r = 0; r < 2; ++r){
      float part[4] = {0.f, 0.f, 0.f, 0.f};
      #pragma unroll
      for (int nt = 0; nt < 4; ++nt)
        #pragma unroll
        for (int rr = 0; rr < 4; ++rr)
          part[rr] = fmaf(fmaxf(acc[r][nt][rr], 0.f), we2q[nt], part[rr]);
      #pragma unroll
      for (int rr = 0; rr < 4; ++rr) part[rr] = row16_sum(part[rr]);

      if (q < 4){
        int j2 = jbase + kg*4 + q;
        float ps2 = part[0];
        ps2 = (q == 1) ? part[1] : ps2;
        ps2 = (q == 2) ? part[2] : ps2;
        ps2 = (q == 3) ? part[3] : ps2;
        float lg = ps2 + s_ext[r][j2];
        lrow[r][j2] = (j2 == ip + r) ? spsl : lg;
      }
    }
  }
  __syncthreads();

  // fused dual-row softmax (512 threads, 1 elem per row each)
  float va = lrow[0][tid], vb = lrow[1][tid];
  float ma = va, mb = vb;
  #pragma unroll
  for (int msk = 1; msk < 64; msk <<= 1){
    ma = fmaxf(ma, __shfl_xor(ma, msk));
    mb = fmaxf(mb, __shfl_xor(mb, msk));
  }
  if (lane == 0){ red[w] = ma; red[8 + w] = mb; }
  __syncthreads();
  ma = red[0]; mb = red[8];
  #pragma unroll
  for (int ww = 1; ww < 8; ++ww){
    ma = fmaxf(ma, red[ww]);
    mb = fmaxf(mb, red[8 + ww]);
  }

  float ea = expf((va - ma) * invt);
  float eb = expf((vb - mb) * invt);
  float sa = ea, sb = eb;
  #pragma unroll
  for (int msk = 1; msk < 64; msk <<= 1){
    sa += __shfl_xor(sa, msk);
    sb += __shfl_xor(sb, msk);
  }
  if (lane == 0){ red[16 + w] = sa; red[24 + w] = sb; }
  __syncthreads();
  sa = red[16]; sb = red[24];
  #pragma unroll
  for (int ww = 1; ww < 8; ++ww){
    sa += red[16 + ww];
    sb += red[24 + ww];
  }

  unsym[(size_t)(b*NN + ip)*NN + tid]       = ea / sa;
  unsym[(size_t)(b*NN + ip + 1)*NN + tid]   = eb / sb;
}

// ---------------- Kernel D: symmetrize + renormalize ----------------
__global__ __launch_bounds__(256) void k_sym(
    const float* __restrict__ u, float* __restrict__ out){
  int blk = blockIdx.x;
  int b = blk >> 9, i = blk & (NN-1);
  int tid = threadIdx.x;
  const float* urow = u + (size_t)(b*NN + i) * NN;
  float v0, v1, rs;
  {
    int j0 = tid, j1 = tid + 256;
    float a1 = urow[j0];
    float a2 = u[(size_t)(b*NN + j0) * NN + i];
    v0 = 0.5f*(a1 + a2);
    float a3 = urow[j1];
    float a4 = u[(size_t)(b*NN + j1) * NN + i];
    v1 = 0.5f*(a3 + a4);
    rs = v0 + v1;
  }
  int lane = tid & 63, w = tid >> 6;
  #pragma unroll
  for (int msk = 1; msk < 64; msk <<= 1) rs += __shfl_xor(rs, msk);
  __shared__ float red[4];
  if (lane == 0) red[w] = rs;
  __syncthreads();
  rs = red[0] + red[1] + red[2] + red[3];
  float inv = 1.f / fmaxf(rs, 1e-6f);
  float* orow = out + (size_t)(b*NN + i) * NN;
  orow[tid]       = v0 * inv;
  orow[tid + 256] = v1 * inv;
}

extern "C" void kernel_launch(void* const* d_in, const int* in_sizes, int n_in,
                              void* d_out, int out_size, void* d_ws, size_t ws_size,
                              hipStream_t stream){
  const float* x      = (const float*)d_in[0];
  const float* mask   = (const float*)d_in[1];
  const float* sctx   = (const float*)d_in[2];
  const float* coords = (const float*)d_in[3];
  const float* W1     = (const float*)d_in[4];
  const float* b1     = (const float*)d_in[5];
  const float* W2     = (const float*)d_in[6];
  const float* b2     = (const float*)d_in[7];
  const float* We1    = (const float*)d_in[8];
  const float* be1    = (const float*)d_in[9];
  const float* We2    = (const float*)d_in[10];
  const float* be2    = (const float*)d_in[11];
  const float* sl     = (const float*)d_in[12];
  const float* ps     = (const float*)d_in[13];
  const float* ss     = (const float*)d_in[14];
  const float* tp     = (const float*)d_in[15];

  float*    ws    = (float*)d_ws;
  float*    hgp   = ws + OFF_H;
  float*    pvecp = ws + OFF_PVEC;
  unsigned* hf16p = (unsigned*)(ws + OFF_HF16);
  unsigned* hn16p = (unsigned*)(ws + OFF_HNF16);
  short*    wa16p = (short*)(ws + OFF_WA16);
  float*    wjfp  = ws + OFF_WJF;
  float*    wpfp  = ws + OFF_WPF;
  float*    gext  = ws + OFF_GEXT;
  float*    unsym = ws + OFF_UNSYM;
  float*    out   = (float*)d_out;

  k_front <<<304, 256, 0, stream>>>(x, mask, sctx, W1, b1, W2, b2, We1, be1,
                                    hgp, pvecp, hf16p, hn16p, wa16p, wjfp, wpfp);
  k_extra <<<dim3(NB, 32, 4), 256, 0, stream>>>(hn16p, coords, ss, ps, be2, gext);
  k_logits<<<NB*NN/2, 512, 0, stream>>>(hgp, pvecp, hf16p, wa16p, wjfp, wpfp,
                                        We2, gext, sl, tp, unsym);
  k_sym   <<<NB*NN, 256, 0, stream>>>(unsym, out);
}